// Round 26
// baseline (320.616 us; speedup 1.0000x reference)
//
#include <hip/hip_runtime.h>
#include <cstdint>

#define BB    256
#define NNODE 256
#define PP2   64
#define DD    128
#define LLAY  2
#define KNN   9
#define FFND  512
#define BNROWS (BB*NNODE)   // 65536

#define LRELU_(v) ((v) >= 0.f ? (v) : 0.01f*(v))

enum { ACT_NONE = 0, ACT_LRELU = 1 };

typedef short  short8_t  __attribute__((ext_vector_type(8)));
typedef float  f32x4     __attribute__((ext_vector_type(4)));
typedef unsigned short us4 __attribute__((ext_vector_type(4)));
typedef unsigned short us8 __attribute__((ext_vector_type(8)));

__device__ inline unsigned short f2bf(float x) {
    unsigned u = __float_as_uint(x);
    unsigned r = (u + 0x7FFFu + ((u >> 16) & 1u)) >> 16;
    return (unsigned short)r;
}
__device__ inline float bf2f(unsigned short h) {
    return __uint_as_float(((unsigned)h) << 16);
}

// async global->LDS, 16B per lane; LDS dest must be wave-uniform base.
__device__ inline void gload16(const void* src, void* dst) {
    __builtin_amdgcn_global_load_lds(
        (const __attribute__((address_space(1))) void*)src,
        (__attribute__((address_space(3))) void*)dst, 16, 0, 0);
}

// Stage a BK=64 bf16 tile (ROWS x 64 elems, 128B rows) from row-major global
// (element stride Kel, starting col k0) into LINEAR LDS via global_load_lds.
// Source address carries the inverse XOR swizzle; reads apply the same XOR.
template<int ROWS, int WAVES>
__device__ inline void stage64g(const unsigned short* __restrict__ g, size_t rowbase,
                                int Kel, int k0, unsigned short* lds, int w, int lane)
{
    constexpr int PER = (ROWS*128/1024) / WAVES;
    #pragma unroll
    for (int i = 0; i < PER; ++i) {
        const int inst = w + i*WAVES;                 // wave-uniform
        const unsigned o  = (unsigned)inst*1024u + (unsigned)lane*16u;
        const int      r  = (int)(o >> 7);
        const unsigned cb = o & 127u;
        const unsigned cs = cb ^ ((unsigned)(r & 7) << 4);
        gload16((const char*)(g + (rowbase + (size_t)r)*(size_t)Kel + k0) + cs,
                (char*)lds + (size_t)inst*1024u);
    }
}

// swizzled fragment read from a linear BK=64 tile
__device__ inline short8_t frag64(const unsigned short* lds, int r, int cb) {
    return *reinterpret_cast<const short8_t*>(
        (const char*)lds + (size_t)r*128 + (unsigned)(cb ^ ((r & 7) << 4)));
}

// swizzled 16B (8 cols) read from a BK=64 tile at column-byte cb (mult of 16)
__device__ inline us8 read8sw(const unsigned short* lds, int r, unsigned cb) {
    return *reinterpret_cast<const us8*>(
        (const char*)lds + (size_t)r*128 + (cb ^ ((unsigned)(r & 7) << 4)));
}

// 16-lane-group min (per DPP row); result in ALL lanes of each 16-group.
__device__ inline unsigned grp16_min_u32(unsigned v) {
    unsigned t;
    t = (unsigned)__builtin_amdgcn_update_dpp(-1, (int)v, 0xB1,  0xF, 0xF, false); v = t < v ? t : v; // quad_perm [1,0,3,2]
    t = (unsigned)__builtin_amdgcn_update_dpp(-1, (int)v, 0x4E,  0xF, 0xF, false); v = t < v ? t : v; // quad_perm [2,3,0,1]
    t = (unsigned)__builtin_amdgcn_update_dpp(-1, (int)v, 0x124, 0xF, 0xF, false); v = t < v ? t : v; // row_ror:4
    t = (unsigned)__builtin_amdgcn_update_dpp(-1, (int)v, 0x128, 0xF, 0xF, false); v = t < v ? t : v; // row_ror:8
    return v;
}

// 16-lane (DPP row) sum; result valid in lane 15 of each 16-lane row.
__device__ inline float dpp_rowsum16(float v) {
    float t;
    t = __uint_as_float((unsigned)__builtin_amdgcn_update_dpp(0, (int)__float_as_uint(v), 0x111, 0xF, 0xF, false)); v += t;
    t = __uint_as_float((unsigned)__builtin_amdgcn_update_dpp(0, (int)__float_as_uint(v), 0x112, 0xF, 0xF, false)); v += t;
    t = __uint_as_float((unsigned)__builtin_amdgcn_update_dpp(0, (int)__float_as_uint(v), 0x114, 0xF, 0xF, false)); v += t;
    t = __uint_as_float((unsigned)__builtin_amdgcn_update_dpp(0, (int)__float_as_uint(v), 0x118, 0xF, 0xF, false)); v += t;
    return v;
}

// ---------------------------------------------------------------------------
// bf16 MFMA GEMM, BK=64, global_load_lds staging. (head only now)
// ---------------------------------------------------------------------------
template<int ACT, bool RES, bool MASK, bool OUTF, bool OUTB, bool OUTS>
__global__ __launch_bounds__(256)
void bgemm_k(const unsigned short* __restrict__ A,
             const unsigned short* __restrict__ W,
             const float* __restrict__ bias,
             const float* __restrict__ resp,
             const int* __restrict__ mask,
             float* __restrict__ Cf, unsigned short* __restrict__ Cb,
             unsigned short* Ohi, unsigned short* Olo,
             int M, int N, int K)
{
    __shared__ __align__(16) unsigned short As[128*64];
    __shared__ __align__(16) unsigned short Bs[128*64];

    const int tid  = threadIdx.x;
    const int lane = tid & 63;
    const int w    = tid >> 6;
    const int wr   = w >> 1, wc = w & 1;
    const int row0 = blockIdx.x * 128;
    const int col0 = blockIdx.y * 128;
    const int l15  = lane & 15;
    const int ko   = lane >> 4;

    f32x4 acc[4][4];
    #pragma unroll
    for (int m = 0; m < 4; ++m)
        #pragma unroll
        for (int n = 0; n < 4; ++n) acc[m][n] = (f32x4){0.f,0.f,0.f,0.f};

    for (int k0 = 0; k0 < K; k0 += 64) {
        stage64g<128,4>(A, (size_t)row0, K, k0, As, w, lane);
        stage64g<128,4>(W, (size_t)col0, K, k0, Bs, w, lane);
        __syncthreads();
        #pragma unroll
        for (int ks = 0; ks < 2; ++ks) {
            short8_t aF[4], bF[4];
            #pragma unroll
            for (int m = 0; m < 4; ++m)
                aF[m] = frag64(As, wr*64 + m*16 + l15, ks*64 + ko*16);
            #pragma unroll
            for (int n = 0; n < 4; ++n)
                bF[n] = frag64(Bs, wc*64 + n*16 + l15, ks*64 + ko*16);
            #pragma unroll
            for (int m = 0; m < 4; ++m)
                #pragma unroll
                for (int n = 0; n < 4; ++n)
                    acc[m][n] = __builtin_amdgcn_mfma_f32_16x16x32_bf16(aF[m], bF[n], acc[m][n], 0, 0, 0);
        }
        __syncthreads();
    }

    #pragma unroll
    for (int m = 0; m < 4; ++m) {
        const int rbase = row0 + wr*64 + m*16 + ko*4;
        #pragma unroll
        for (int n = 0; n < 4; ++n) {
            const int col = col0 + wc*64 + n*16 + l15;
            const float bv = bias[col];
            #pragma unroll
            for (int r = 0; r < 4; ++r) {
                const int row = rbase + r;
                float v = acc[m][n][r] + bv;
                if constexpr (ACT == ACT_LRELU) v = LRELU_(v);
                if constexpr (RES)  v += resp[(size_t)row*N + col];
                if constexpr (MASK) v *= (mask[row] != 0) ? 1.f : 0.f;
                if constexpr (OUTF) Cf[(size_t)row*N + col] = v;
                if constexpr (OUTB) Cb[(size_t)row*N + col] = f2bf(v);
                if constexpr (OUTS) {
                    unsigned short h = f2bf(v);
                    Ohi[(size_t)row*N + col] = h;
                    Olo[(size_t)row*N + col] = f2bf(v - bf2f(h));
                }
            }
        }
    }
}

// ---------------------------------------------------------------------------
// bf16 MFMA GEMM fused with full-row LayerNorm epilogue (BK=64).
// MODE 1: bf16 out. MODE 2: split hi/lo ONLY (no fp32).
// ---------------------------------------------------------------------------
template<int WR, int WC, bool DO_LRELU, bool MASKMUL, int MODE, bool AF32>
__global__ __launch_bounds__(WR*WC*64)
void bgemm_ln_k(const void* __restrict__ Ap,
                const unsigned short* __restrict__ W,
                const float* __restrict__ bias,
                const float* __restrict__ gam,
                const float* __restrict__ bet,
                const int* __restrict__ mask,
                void* __restrict__ outv,
                unsigned short* __restrict__ ohi, unsigned short* __restrict__ olo,
                int K)
{
    constexpr int BM = WR*64;
    constexpr int BN = WC*64;
    constexpr int THREADS = WR*WC*64;
    constexpr int WAVES = THREADS/64;
    __shared__ __align__(16) unsigned short As[BM*64];
    __shared__ __align__(16) unsigned short Bs[BN*64];
    __shared__ float red_s[WC][BM];
    __shared__ float red_q[WC][BM];
    __shared__ float mu_l[BM];
    __shared__ float rs_l[BM];

    const int tid  = threadIdx.x;
    const int lane = tid & 63;
    const int w    = tid >> 6;
    const int wr   = w / WC, wc = w % WC;
    const int row0 = blockIdx.x * BM;
    const int l15  = lane & 15;
    const int ko   = lane >> 4;

    f32x4 acc[4][4];
    #pragma unroll
    for (int m = 0; m < 4; ++m)
        #pragma unroll
        for (int n = 0; n < 4; ++n) acc[m][n] = (f32x4){0.f,0.f,0.f,0.f};

    for (int k0 = 0; k0 < K; k0 += 64) {
        if constexpr (AF32) {
            const float* Af = (const float*)Ap;
            constexpr int CH = (BM*8)/THREADS;    // 16B chunks per thread
            #pragma unroll
            for (int i = 0; i < CH; ++i) {
                const int q = i*THREADS + tid;
                const unsigned o  = (unsigned)q*16u;
                const int      r  = (int)(o >> 7);
                const unsigned cb = o & 127u;
                const unsigned cs = cb ^ ((unsigned)(r & 7) << 4);
                const float* src = Af + (size_t)(row0 + r)*K + k0 + (cs >> 1);
                const float4 f0 = *reinterpret_cast<const float4*>(src);
                const float4 f1 = *reinterpret_cast<const float4*>(src + 4);
                short8_t v;
                v[0]=(short)f2bf(f0.x); v[1]=(short)f2bf(f0.y); v[2]=(short)f2bf(f0.z); v[3]=(short)f2bf(f0.w);
                v[4]=(short)f2bf(f1.x); v[5]=(short)f2bf(f1.y); v[6]=(short)f2bf(f1.z); v[7]=(short)f2bf(f1.w);
                *reinterpret_cast<short8_t*>((char*)As + o) = v;
            }
        } else {
            stage64g<BM,WAVES>((const unsigned short*)Ap, (size_t)row0, K, k0, As, w, lane);
        }
        stage64g<BN,WAVES>(W, 0, K, k0, Bs, w, lane);
        __syncthreads();
        #pragma unroll
        for (int ks = 0; ks < 2; ++ks) {
            short8_t aF[4], bF[4];
            #pragma unroll
            for (int m = 0; m < 4; ++m)
                aF[m] = frag64(As, wr*64 + m*16 + l15, ks*64 + ko*16);
            #pragma unroll
            for (int n = 0; n < 4; ++n)
                bF[n] = frag64(Bs, wc*64 + n*16 + l15, ks*64 + ko*16);
            #pragma unroll
            for (int m = 0; m < 4; ++m)
                #pragma unroll
                for (int n = 0; n < 4; ++n)
                    acc[m][n] = __builtin_amdgcn_mfma_f32_16x16x32_bf16(aF[m], bF[n], acc[m][n], 0, 0, 0);
        }
        __syncthreads();
    }

    float bv[4];
    #pragma unroll
    for (int n = 0; n < 4; ++n) bv[n] = bias[wc*64 + n*16 + l15];
    #pragma unroll
    for (int m = 0; m < 4; ++m)
        #pragma unroll
        for (int n = 0; n < 4; ++n)
            #pragma unroll
            for (int r = 0; r < 4; ++r) acc[m][n][r] += bv[n];

    #pragma unroll
    for (int m = 0; m < 4; ++m) {
        #pragma unroll
        for (int r = 0; r < 4; ++r) {
            float s = acc[m][0][r] + acc[m][1][r] + acc[m][2][r] + acc[m][3][r];
            float q = acc[m][0][r]*acc[m][0][r] + acc[m][1][r]*acc[m][1][r]
                    + acc[m][2][r]*acc[m][2][r] + acc[m][3][r]*acc[m][3][r];
            s = dpp_rowsum16(s);
            q = dpp_rowsum16(q);
            if (l15 == 15) {
                int rl = wr*64 + m*16 + ko*4 + r;
                red_s[wc][rl] = s;
                red_q[wc][rl] = q;
            }
        }
    }
    __syncthreads();
    if (tid < BM) {
        float s = 0.f, q = 0.f;
        #pragma unroll
        for (int c2 = 0; c2 < WC; ++c2) { s += red_s[c2][tid]; q += red_q[c2][tid]; }
        float mu  = s * (1.0f/BN);
        float var = q * (1.0f/BN) - mu*mu;
        mu_l[tid] = mu;
        rs_l[tid] = rsqrtf(fmaxf(var, 0.f) + 1e-5f);
    }
    __syncthreads();

    float gm[4], bt[4];
    #pragma unroll
    for (int n = 0; n < 4; ++n) {
        int col = wc*64 + n*16 + l15;
        gm[n] = gam[col]; bt[n] = bet[col];
    }
    #pragma unroll
    for (int m = 0; m < 4; ++m) {
        #pragma unroll
        for (int r = 0; r < 4; ++r) {
            const int rl  = wr*64 + m*16 + ko*4 + r;
            const int row = row0 + rl;
            const float mu = mu_l[rl], rs = rs_l[rl];
            float mf = 1.f;
            if constexpr (MASKMUL) mf = (mask[row] != 0) ? 1.f : 0.f;
            #pragma unroll
            for (int n = 0; n < 4; ++n) {
                const int col = wc*64 + n*16 + l15;
                float y = (acc[m][n][r] - mu) * rs * gm[n] + bt[n];
                if constexpr (DO_LRELU) y = LRELU_(y);
                if constexpr (MASKMUL)  y *= mf;
                if constexpr (MODE == 1) {
                    ((unsigned short*)outv)[(size_t)row*BN + col] = f2bf(y);
                } else {
                    unsigned short h = f2bf(y);
                    ohi[(size_t)row*BN + col] = h;
                    olo[(size_t)row*BN + col] = f2bf(y - bf2f(h));
                }
            }
        }
    }
}

// ---------------------------------------------------------------------------
// FULL ViG BLOCK: fc1 + dist + top-9 + gather + conv + fc2 + FFN,
// ONE block per batch (1024 thr, 16 waves). No cat/h2 in HBM.
// BUF lifecycle: x split -> h split -> [h_hi | mrel] (= cat in LDS)
//             -> [h2 | Xs] -> [h1_chunk | Xs]. Weights stream through Ws.
// xhi/xlo are read (residual) AND written (new x) - not const.
// ---------------------------------------------------------------------------
__global__ __launch_bounds__(1024)
void vig_block_k(unsigned short* xhi,
                 unsigned short* xlo,
                 const unsigned short* __restrict__ Whi,  // fc1 [128][128]
                 const unsigned short* __restrict__ Wlo,  // fc1 [128][128]
                 const float* __restrict__ fc1b,
                 const int* __restrict__ mask,
                 const unsigned short* __restrict__ Wc,   // conv [128][256]
                 const float* __restrict__ cbias,
                 const unsigned short* __restrict__ W2c,  // fc2 [128][128]
                 const float* __restrict__ fb,
                 const unsigned short* __restrict__ W1,   // ffn1 [512][128]
                 const float* __restrict__ b1,
                 const unsigned short* __restrict__ W2f,  // ffn2 [128][512]
                 const float* __restrict__ b2)
{
    __shared__ __align__(16) unsigned short BUF[4][NNODE*64];   // 128KB
    __shared__ __align__(16) unsigned short Ws[128*64];         // 16KB weight tile
    __shared__ float x2s[NNODE];
    __shared__ unsigned char idx_s[NNODE*KNN];
    __shared__ unsigned char msk_s[NNODE];

    const int b    = blockIdx.x;
    const int tid  = threadIdx.x;
    const int lane = tid & 63;
    const int w    = tid >> 6;          // 0..15
    const int l15  = lane & 15;
    const int g    = lane >> 4;         // 0..3

    const unsigned short* Xhi = xhi + (size_t)b*NNODE*DD;
    const unsigned short* Xlo = xlo + (size_t)b*NNODE*DD;
    const int* mkb = mask + b*NNODE;

    // ---- stage x split (both k-tiles) ----
    stage64g<NNODE,16>(Xhi, 0, DD, 0,  &BUF[0][0], w, lane);
    stage64g<NNODE,16>(Xhi, 0, DD, 64, &BUF[1][0], w, lane);
    stage64g<NNODE,16>(Xlo, 0, DD, 0,  &BUF[2][0], w, lane);
    stage64g<NNODE,16>(Xlo, 0, DD, 64, &BUF[3][0], w, lane);
    if (tid < NNODE) msk_s[tid] = (mkb[tid] != 0) ? 1 : 0;
    __syncthreads();

    const int arow = w*16 + l15;        // 0..255

    // ---- fc1: h = x @ W^T + b, 3 split phases; weights streamed ----
    f32x4 hacc[8];
    #pragma unroll
    for (int n = 0; n < 8; ++n) hacc[n] = (f32x4){0.f,0.f,0.f,0.f};

    #pragma unroll
    for (int wp = 0; wp < 4; ++wp) {                 // (Whi,kt0)(Whi,kt1)(Wlo,kt0)(Wlo,kt1)
        const unsigned short* Wsrc = (wp < 2) ? Whi : Wlo;
        const int kt = wp & 1;
        stage64g<128,16>(Wsrc, 0, DD, kt*64, Ws, w, lane);
        __syncthreads();
        const int nAv = (wp < 2) ? 2 : 1;            // Whi: x_hi + x_lo; Wlo: x_hi only
        for (int av = 0; av < nAv; ++av) {
            const unsigned short* At = (av == 0) ? &BUF[kt][0] : &BUF[2+kt][0];
            #pragma unroll
            for (int ks = 0; ks < 2; ++ks) {
                short8_t aF = frag64(At, arow, ks*64 + g*16);
                #pragma unroll
                for (int n = 0; n < 8; ++n) {
                    short8_t bF = frag64(Ws, n*16 + l15, ks*64 + g*16);
                    hacc[n] = __builtin_amdgcn_mfma_f32_16x16x32_bf16(aF, bF, hacc[n], 0, 0, 0);
                }
            }
        }
        __syncthreads();                             // Ws reads + (last) x reads done
    }

    // ---- bias + split + x2; write h into BUF (x is dead) ----
    {
        float qr[4] = {0.f, 0.f, 0.f, 0.f};
        #pragma unroll
        for (int n = 0; n < 8; ++n) {
            const int col = n*16 + l15;
            const float bv = fc1b[col];
            const int kt = col >> 6;
            const unsigned bc = (unsigned)((col & 63) * 2);
            #pragma unroll
            for (int r = 0; r < 4; ++r) {
                const int row = w*16 + g*4 + r;
                float v = hacc[n][r] + bv;
                unsigned short hh = f2bf(v);
                unsigned short hl = f2bf(v - bf2f(hh));
                const unsigned off = (unsigned)(row*128) + (bc ^ ((unsigned)(row & 7) << 4));
                *(unsigned short*)((char*)&BUF[kt][0]   + off) = hh;
                *(unsigned short*)((char*)&BUF[2+kt][0] + off) = hl;
                float vv = bf2f(hh) + bf2f(hl);
                qr[r] += vv*vv;
            }
        }
        #pragma unroll
        for (int r = 0; r < 4; ++r) {
            float q = dpp_rowsum16(qr[r]);
            if (l15 == 15) x2s[w*16 + g*4 + r] = q;
        }
    }
    __syncthreads();

    // ---- distance MFMA (h resident) ----
    {
        f32x4 acc[16];
        #pragma unroll
        for (int n = 0; n < 16; ++n) acc[n] = (f32x4){0.f,0.f,0.f,0.f};

        __builtin_amdgcn_s_setprio(1);
        #pragma unroll
        for (int kt = 0; kt < 2; ++kt) {
            #pragma unroll
            for (int ks = 0; ks < 2; ++ks) {
                short8_t aH = frag64(&BUF[kt][0],   arow, ks*64 + g*16);
                short8_t aL = frag64(&BUF[2+kt][0], arow, ks*64 + g*16);
                #pragma unroll
                for (int n = 0; n < 16; ++n) {
                    int brow = n*16 + l15;
                    short8_t bH = frag64(&BUF[kt][0],   brow, ks*64 + g*16);
                    short8_t bL = frag64(&BUF[2+kt][0], brow, ks*64 + g*16);
                    acc[n] = __builtin_amdgcn_mfma_f32_16x16x32_bf16(aH, bH, acc[n], 0, 0, 0); // hi.hi
                    acc[n] = __builtin_amdgcn_mfma_f32_16x16x32_bf16(aL, bH, acc[n], 0, 0, 0); // lo.hi
                    acc[n] = __builtin_amdgcn_mfma_f32_16x16x32_bf16(aH, bL, acc[n], 0, 0, 0); // hi.lo
                }
            }
        }
        __builtin_amdgcn_s_setprio(0);

        float x2c[16]; unsigned mk[16];
        #pragma unroll
        for (int n = 0; n < 16; ++n) {
            int col = n*16 + l15;
            x2c[n] = x2s[col];
            mk[n]  = (unsigned)msk_s[col];
        }

        #pragma unroll
        for (int r = 0; r < 4; ++r) {
            const int rb = w*16 + r;
            if ((msk_s[rb] | msk_s[rb+4] | msk_s[rb+8] | msk_s[rb+12]) == 0) continue;
            const int lrow = w*16 + g*4 + r;          // this wave's rows only
            const float x2r = x2s[lrow];
            unsigned key[16];
            #pragma unroll
            for (int n = 0; n < 16; ++n) {
                float v = x2r + x2c[n] - 2.0f*acc[n][r];
                if (!mk[n]) v = 1e10f;
                unsigned u = __float_as_uint(v);
                u = (u & 0x80000000u) ? ~u : (u | 0x80000000u);
                key[n] = (u & 0xFFFFFF00u) | (unsigned)(n*16 + l15);
            }
            for (int it = 0; it < KNN; ++it) {
                unsigned a0 = key[0]  < key[1]  ? key[0]  : key[1];
                unsigned a1 = key[2]  < key[3]  ? key[2]  : key[3];
                unsigned a2 = key[4]  < key[5]  ? key[4]  : key[5];
                unsigned a3 = key[6]  < key[7]  ? key[6]  : key[7];
                unsigned a4 = key[8]  < key[9]  ? key[8]  : key[9];
                unsigned a5 = key[10] < key[11] ? key[10] : key[11];
                unsigned a6 = key[12] < key[13] ? key[12] : key[13];
                unsigned a7 = key[14] < key[15] ? key[14] : key[15];
                unsigned b0 = a0 < a1 ? a0 : a1;
                unsigned b1_ = a2 < a3 ? a2 : a3;
                unsigned b2_ = a4 < a5 ? a4 : a5;
                unsigned b3 = a6 < a7 ? a6 : a7;
                unsigned c0 = b0 < b1_ ? b0 : b1_;
                unsigned c1 = b2_ < b3 ? b2_ : b3;
                unsigned lmin = c0 < c1 ? c0 : c1;
                unsigned gmin = grp16_min_u32(lmin);
                if (l15 == 0) idx_s[lrow*KNN + it] = (unsigned char)(gmin & 0xFFu);
                #pragma unroll
                for (int n = 0; n < 16; ++n)
                    if (key[n] == gmin) key[n] = 0xFFFFFFFFu;
            }
        }
    }
    // NO barrier: gather reads only this wave's idx rows (same-wave DS order).

    // ---- gather: mrel into regs, then overwrite lo planes (BUF[2..3]) ----
    {
        us8 o2s[2][2];
        const int gi = lane & 7;                       // granule 0..7 (8 cols)
        const unsigned cb = (unsigned)(gi * 16);       // byte col within tile
        #pragma unroll
        for (int kt = 0; kt < 2; ++kt) {
            #pragma unroll
            for (int p = 0; p < 2; ++p) {
                const int rl = w*16 + p*8 + (lane >> 3);   // this wave's row
                us8 h8 = read8sw(&BUF[kt][0],   rl, cb);
                us8 l8 = read8sw(&BUF[2+kt][0], rl, cb);
                float hi[8], m[8];
                #pragma unroll
                for (int d = 0; d < 8; ++d) { hi[d] = bf2f(h8[d]) + bf2f(l8[d]); m[d] = -1e9f; }
                bool any = false;
                #pragma unroll
                for (int q = 0; q < KNN; ++q) {
                    int j = idx_s[rl*KNN + q];
                    if (msk_s[j]) {
                        any = true;
                        us8 a = read8sw(&BUF[kt][0],   j, cb);
                        us8 o = read8sw(&BUF[2+kt][0], j, cb);
                        #pragma unroll
                        for (int d = 0; d < 8; ++d)
                            m[d] = fmaxf(m[d], bf2f(a[d]) + bf2f(o[d]));
                    }
                }
                #pragma unroll
                for (int d = 0; d < 8; ++d)
                    o2s[kt][p][d] = any ? f2bf(m[d] - hi[d]) : (unsigned short)0;
            }
        }
        __syncthreads();   // ALL waves done reading lo/hi for gather
        #pragma unroll
        for (int kt = 0; kt < 2; ++kt) {
            #pragma unroll
            for (int p = 0; p < 2; ++p) {
                const int rl = w*16 + p*8 + (lane >> 3);
                *reinterpret_cast<us8*>((char*)&BUF[2+kt][0] + (size_t)rl*128
                    + (cb ^ ((unsigned)(rl & 7) << 4))) = o2s[kt][p];
            }
        }
    }
    __syncthreads();   // BUF = cat in LDS: [h_hi kt0, h_hi kt1, mrel kt0, mrel kt1]

    // ---- conv: accc = cat @ Wc^T  (k = 256, 4 tiles = the 4 BUF planes) ----
    f32x4 accc[8];
    #pragma unroll
    for (int n = 0; n < 8; ++n) accc[n] = (f32x4){0.f,0.f,0.f,0.f};
    #pragma unroll
    for (int kt4 = 0; kt4 < 4; ++kt4) {
        stage64g<128,16>(Wc, 0, 256, kt4*64, Ws, w, lane);
        __syncthreads();
        #pragma unroll
        for (int ks = 0; ks < 2; ++ks) {
            short8_t aF = frag64(&BUF[kt4][0], arow, ks*64 + g*16);
            #pragma unroll
            for (int n = 0; n < 8; ++n) {
                short8_t bF = frag64(Ws, n*16 + l15, ks*64 + g*16);
                accc[n] = __builtin_amdgcn_mfma_f32_16x16x32_bf16(aF, bF, accc[n], 0, 0, 0);
            }
        }
        __syncthreads();
    }

    // h2 = lrelu(accc + cb) -> BUF[0..1] (cat dead)
    #pragma unroll
    for (int n = 0; n < 8; ++n) {
        const int col = n*16 + l15;
        const float bv = cbias[col];
        const int kt = col >> 6;
        const unsigned bc = (unsigned)((col & 63) * 2);
        #pragma unroll
        for (int r = 0; r < 4; ++r) {
            const int row = w*16 + g*4 + r;
            float v = LRELU_(accc[n][r] + bv);
            *(unsigned short*)((char*)&BUF[kt][0] + row*128
                + (bc ^ ((unsigned)(row & 7) << 4))) = f2bf(v);
        }
    }
    __syncthreads();

    // ---- fc2: accx = h2 @ W2c^T ----
    f32x4 accx[8];
    #pragma unroll
    for (int n = 0; n < 8; ++n) accx[n] = (f32x4){0.f,0.f,0.f,0.f};
    #pragma unroll
    for (int kt = 0; kt < 2; ++kt) {
        stage64g<128,16>(W2c, 0, 128, kt*64, Ws, w, lane);
        __syncthreads();
        #pragma unroll
        for (int ks = 0; ks < 2; ++ks) {
            short8_t aF = frag64(&BUF[kt][0], arow, ks*64 + g*16);
            #pragma unroll
            for (int n = 0; n < 8; ++n) {
                short8_t bF = frag64(Ws, n*16 + l15, ks*64 + g*16);
                accx[n] = __builtin_amdgcn_mfma_f32_16x16x32_bf16(aF, bF, accx[n], 0, 0, 0);
            }
        }
        __syncthreads();
    }

    // xn = accx + fb + residual(x split from HBM); Xs = bf16(xn) -> BUF[2..3]
    float xn[8][4];
    #pragma unroll
    for (int n = 0; n < 8; ++n) {
        const int col = n*16 + l15;
        const float bv = fb[col];
        const int kt = col >> 6;
        const unsigned bc = (unsigned)((col & 63) * 2);
        #pragma unroll
        for (int r = 0; r < 4; ++r) {
            const int row = w*16 + g*4 + r;
            const size_t gix = (size_t)(b*NNODE + row)*DD + col;
            float res = bf2f(xhi[gix]) + bf2f(xlo[gix]);
            float v = accx[n][r] + bv + res;
            xn[n][r] = v;
            *(unsigned short*)((char*)&BUF[2+kt][0] + row*128
                + (bc ^ ((unsigned)(row & 7) << 4))) = f2bf(v);
        }
    }
    __syncthreads();

    // ---- FFN: acc2 = lrelu(Xs@W1^T + b1) @ W2f^T ----
    f32x4 acc2[8];
    #pragma unroll
    for (int n = 0; n < 8; ++n) acc2[n] = (f32x4){0.f,0.f,0.f,0.f};

    for (int c = 0; c < 4; ++c) {
        f32x4 acc1[8];
        #pragma unroll
        for (int n = 0; n < 8; ++n) acc1[n] = (f32x4){0.f,0.f,0.f,0.f};
        #pragma unroll
        for (int kt = 0; kt < 2; ++kt) {
            stage64g<128,16>(W1, (size_t)(c*128), DD, kt*64, Ws, w, lane);
            __syncthreads();
            #pragma unroll
            for (int ks = 0; ks < 2; ++ks) {
                short8_t aF = frag64(&BUF[2+kt][0], arow, ks*64 + g*16);
                #pragma unroll
                for (int n = 0; n < 8; ++n) {
                    short8_t bF = frag64(Ws, n*16 + l15, ks*64 + g*16);
                    acc1[n] = __builtin_amdgcn_mfma_f32_16x16x32_bf16(aF, bF, acc1[n], 0, 0, 0);
                }
            }
            __syncthreads();
        }
        // h1 chunk = lrelu(acc1 + b1) -> BUF[0..1] (h2 / prev h1 dead)
        #pragma unroll
        for (int n = 0; n < 8; ++n) {
            const int col = n*16 + l15;
            const float bv = b1[c*128 + col];
            const int kt = col >> 6;
            const unsigned bc = (unsigned)((col & 63) * 2);
            #pragma unroll
            for (int r = 0; r < 4; ++r) {
                const int row = w*16 + g*4 + r;
                float v = LRELU_(acc1[n][r] + bv);
                *(unsigned short*)((char*)&BUF[kt][0] + row*128
                    + (bc ^ ((unsigned)(row & 7) << 4))) = f2bf(v);
            }
        }
        __syncthreads();
        #pragma unroll
        for (int kt = 0; kt < 2; ++kt) {
            stage64g<128,16>(W2f, 0, FFND, c*128 + kt*64, Ws, w, lane);
            __syncthreads();
            #pragma unroll
            for (int ks = 0; ks < 2; ++ks) {
                short8_t aF = frag64(&BUF[kt][0], arow, ks*64 + g*16);
                #pragma unroll
                for (int n = 0; n < 8; ++n) {
                    short8_t bF = frag64(Ws, n*16 + l15, ks*64 + g*16);
                    acc2[n] = __builtin_amdgcn_mfma_f32_16x16x32_bf16(aF, bF, acc2[n], 0, 0, 0);
                }
            }
            __syncthreads();
        }
    }

    // ---- epilogue: x = acc2 + b2 + xn, masked; write split ----
    #pragma unroll
    for (int n = 0; n < 8; ++n) {
        const int col = n*16 + l15;
        const float bv = b2[col];
        #pragma unroll
        for (int r = 0; r < 4; ++r) {
            const int row = w*16 + g*4 + r;
            const size_t gix = (size_t)(b*NNODE + row)*DD + col;
            float v = acc2[n][r] + bv + xn[n][r];
            v *= msk_s[row] ? 1.f : 0.f;
            unsigned short h = f2bf(v);
            xhi[gix] = h;
            xlo[gix] = f2bf(v - bf2f(h));
        }
    }
}

__global__ __launch_bounds__(128)
void pool_k(const unsigned short* __restrict__ xhi, const unsigned short* __restrict__ xlo,
            const int* __restrict__ mask,
            float* __restrict__ g, unsigned short* __restrict__ gbf)
{
    const int b = blockIdx.x, c = threadIdx.x;
    float s = 0.f; int cnt = 0;
    for (int n = 0; n < NNODE; ++n) {
        const size_t ix = ((size_t)b*NNODE + n)*DD + c;
        s += bf2f(xhi[ix]) + bf2f(xlo[ix]);
        cnt += (mask[b*NNODE + n] != 0) ? 1 : 0;
    }
    float v = s / fmaxf((float)cnt, 1.0f);
    g[b*DD + c] = v;
    gbf[b*DD + c] = f2bf(v);
}

// ---------------------------------------------------------------------------
// All weight transpose-casts in ONE kernel (compile-time job table).
// ---------------------------------------------------------------------------
__global__ __launch_bounds__(256)
void prep_all_k(const float* __restrict__ emb_w1, const float* __restrict__ emb_w2,
                const float* __restrict__ conv_w, const float* __restrict__ fc2_w,
                const float* __restrict__ f1_w,   const float* __restrict__ f2_w,
                const float* __restrict__ fc1_w,  const float* __restrict__ ow1,
                const float* __restrict__ ow2,
                unsigned short* __restrict__ emb_w1t, unsigned short* __restrict__ emb_w2t,
                unsigned short* __restrict__ conv_wt, unsigned short* __restrict__ fc2_wt,
                unsigned short* __restrict__ ffn1_wt, unsigned short* __restrict__ ffn2_wt,
                unsigned short* __restrict__ fc1_wthi, unsigned short* __restrict__ fc1_wtlo,
                unsigned short* __restrict__ ow1t, unsigned short* __restrict__ ow2t)
{
    __shared__ float tile[32][33];
    const int tx = threadIdx.x & 31, ty = threadIdx.x >> 5;

    int bid = blockIdx.x;
    const float* src = nullptr; unsigned short* dst = nullptr; unsigned short* dlo = nullptr;
    int K = 0, N = 0;
    do {
        if (bid < 16)  { src = emb_w1; dst = emb_w1t; K = 64;  N = 256; break; }  bid -= 16;
        if (bid < 32)  { src = emb_w2; dst = emb_w2t; K = 256; N = 128; break; }  bid -= 32;
        if (bid < 64)  { int l = bid >> 5; bid &= 31;
                         src = conv_w + (size_t)l*256*128; dst = conv_wt + (size_t)l*128*256;
                         K = 256; N = 128; break; }                               bid -= 64;
        if (bid < 32)  { int l = bid >> 4; bid &= 15;
                         src = fc2_w + (size_t)l*128*128; dst = fc2_wt + (size_t)l*128*128;
                         K = 128; N = 128; break; }                               bid -= 32;
        if (bid < 128) { int l = bid >> 6; bid &= 63;
                         src = f1_w + (size_t)l*128*512; dst = ffn1_wt + (size_t)l*512*128;
                         K = 128; N = 512; break; }                               bid -= 128;
        if (bid < 128) { int l = bid >> 6; bid &= 63;
                         src = f2_w + (size_t)l*512*128; dst = ffn2_wt + (size_t)l*128*512;
                         K = 512; N = 128; break; }                               bid -= 128;
        if (bid < 32)  { int l = bid >> 4; bid &= 15;
                         src = fc1_w + (size_t)l*128*128;
                         dst = fc1_wthi + (size_t)l*128*128; dlo = fc1_wtlo + (size_t)l*128*128;
                         K = 128; N = 128; break; }                               bid -= 32;
        if (bid < 64)  { src = ow1; dst = ow1t; K = 128; N = 512; break; }        bid -= 64;
        { src = ow2; dst = ow2t; K = 512; N = 2048; }
    } while (0);

    const int nbx = N / 32;
    const int bx = bid % nbx, by = bid / nbx;
    const int k0 = by*32, n0 = bx*32;

    #pragma unroll
    for (int i = ty; i < 32; i += 8)
        tile[i][tx] = src[(size_t)(k0+i)*N + n0+tx];
    __syncthreads();
    #pragma unroll
    for (int i = ty; i < 32; i += 8) {
        float v = tile[tx][i];
        unsigned short h = f2bf(v);
        dst[(size_t)(n0+i)*K + k0+tx] = h;
        if (dlo) dlo[(size_t)(n0+i)*K + k0+tx] = f2bf(v - bf2f(h));
    }
}

// ---------------------------------------------------------------------------
extern "C" void kernel_launch(void* const* d_in, const int* in_sizes, int n_in,
                              void* d_out, int out_size, void* d_ws, size_t ws_size,
                              hipStream_t stream)
{
    const float* nodes  = (const float*)d_in[0];
    const int*   maskp  = (const int*)  d_in[1];
    const float* emb_w1 = (const float*)d_in[2];
    const float* emb_b1 = (const float*)d_in[3];
    const float* ln1_g  = (const float*)d_in[4];
    const float* ln1_b  = (const float*)d_in[5];
    const float* emb_w2 = (const float*)d_in[6];
    const float* emb_b2 = (const float*)d_in[7];
    const float* ln2_g  = (const float*)d_in[8];
    const float* ln2_b  = (const float*)d_in[9];
    const float* fc1_w  = (const float*)d_in[10];
    const float* fc1_b  = (const float*)d_in[11];
    const float* conv_w = (const float*)d_in[12];
    const float* conv_b = (const float*)d_in[13];
    const float* fc2_w  = (const float*)d_in[14];
    const float* fc2_b  = (const float*)d_in[15];
    const float* f1_w   = (const float*)d_in[16];
    const float* f1_b   = (const float*)d_in[17];
    const float* f2_w   = (const float*)d_in[18];
    const float* f2_b   = (const float*)d_in[19];
    const float* ow1    = (const float*)d_in[20];
    const float* ob1    = (const float*)d_in[21];
    const float* ow2    = (const float*)d_in[22];
    const float* ob2    = (const float*)d_in[23];
    float* out = (float*)d_out;

    // ---- workspace layout ----
    char* base = (char*)d_ws;
    char*  H   = base + (size_t)BNROWS*DD*4;            // x_hi/x_lo (residual-carrying)
    char*  BIG = H + (size_t)BNROWS*DD*4;               // t256 embed scratch
    float*          g     = (float*)(BIG + (size_t)BNROWS*2*DD*4);
    unsigned short* g_bf  = (unsigned short*)(g + BB*DD);
    unsigned short* hid2_bf = g_bf + BB*DD;
    unsigned short* wbuf  = hid2_bf + BB*FFND;

    unsigned short* x_hi   = (unsigned short*)H;
    unsigned short* x_lo   = x_hi + (size_t)BNROWS*DD;
    unsigned short* t256_bf= (unsigned short*)base;     // embed phase scratch

    unsigned short* emb_w1t  = wbuf;
    unsigned short* emb_w2t  = emb_w1t + 256*64;
    unsigned short* conv_wt  = emb_w2t + 128*256;
    unsigned short* fc2_wt   = conv_wt + 2*128*256;
    unsigned short* ffn1_wt  = fc2_wt  + 2*128*128;
    unsigned short* ffn2_wt  = ffn1_wt + 2*512*128;
    unsigned short* fc1_wthi = ffn2_wt + 2*128*512;
    unsigned short* fc1_wtlo = fc1_wthi + 2*128*128;
    unsigned short* ow1t     = fc1_wtlo + 2*128*128;
    unsigned short* ow2t     = ow1t + 512*128;

    const dim3 blk(256);

    // ---- all weight transpose-casts (one launch) ----
    prep_all_k<<<1520, blk, 0, stream>>>(
        emb_w1, emb_w2, conv_w, fc2_w, f1_w, f2_w, fc1_w, ow1, ow2,
        emb_w1t, emb_w2t, conv_wt, fc2_wt, ffn1_wt, ffn2_wt,
        fc1_wthi, fc1_wtlo, ow1t, ow2t);

    // ---- Embedding (GEMM + fused LN) ----
    bgemm_ln_k<2,4,true,false,1,true>
        <<<dim3(BNROWS/128), dim3(512), 0, stream>>>
        (nodes, emb_w1t, emb_b1, ln1_g, ln1_b, nullptr, t256_bf, nullptr, nullptr, PP2);
    bgemm_ln_k<2,2,false,true,2,false>
        <<<dim3(BNROWS/128), dim3(256), 0, stream>>>
        (t256_bf, emb_w2t, emb_b2, ln2_g, ln2_b, maskp, nullptr, x_hi, x_lo, 2*DD);

    // ---- ViG blocks (single fused kernel per layer) ----
    for (int l = 0; l < LLAY; ++l) {
        vig_block_k<<<dim3(BB), dim3(1024), 0, stream>>>
            (x_hi, x_lo,
             fc1_wthi + (size_t)l*DD*DD, fc1_wtlo + (size_t)l*DD*DD,
             fc1_b + (size_t)l*DD, maskp,
             conv_wt + (size_t)l*DD*2*DD, conv_b + (size_t)l*DD,
             fc2_wt + (size_t)l*DD*DD,   fc2_b + (size_t)l*DD,
             ffn1_wt + (size_t)l*FFND*DD, f1_b + (size_t)l*FFND,
             ffn2_wt + (size_t)l*DD*FFND, f2_b + (size_t)l*DD);
    }

    // ---- Pool + head (bf16 MFMA) ----
    pool_k<<<BB, 128, 0, stream>>>(x_hi, x_lo, maskp, g, g_bf);
    bgemm_k<ACT_LRELU,false,false,false,true,false>
        <<<dim3(BB/128, 512/128), blk, 0, stream>>>
        (g_bf, ow1t, ob1, nullptr, nullptr, nullptr, hid2_bf, nullptr, nullptr, BB, 512, DD);
    bgemm_k<ACT_NONE,false,false,true,false,false>
        <<<dim3(BB/128, 2048/128), blk, 0, stream>>>
        (hid2_bf, ow2t, ob2, nullptr, nullptr, out, nullptr, nullptr, nullptr, BB, 2048, 512);
}

// Round 27
// 250.101 us; speedup vs baseline: 1.2819x; 1.2819x over previous
//
#include <hip/hip_runtime.h>
#include <cstdint>

#define BB    256
#define NNODE 256
#define PP2   64
#define DD    128
#define LLAY  2
#define KNN   9
#define FFND  512
#define BNROWS (BB*NNODE)   // 65536

#define LRELU_(v) ((v) >= 0.f ? (v) : 0.01f*(v))

enum { ACT_NONE = 0, ACT_LRELU = 1 };

typedef short  short8_t  __attribute__((ext_vector_type(8)));
typedef float  f32x4     __attribute__((ext_vector_type(4)));
typedef unsigned short us4 __attribute__((ext_vector_type(4)));
typedef unsigned short us8 __attribute__((ext_vector_type(8)));

__device__ inline unsigned short f2bf(float x) {
    unsigned u = __float_as_uint(x);
    unsigned r = (u + 0x7FFFu + ((u >> 16) & 1u)) >> 16;
    return (unsigned short)r;
}
__device__ inline float bf2f(unsigned short h) {
    return __uint_as_float(((unsigned)h) << 16);
}

// async global->LDS, 16B per lane; LDS dest must be wave-uniform base.
__device__ inline void gload16(const void* src, void* dst) {
    __builtin_amdgcn_global_load_lds(
        (const __attribute__((address_space(1))) void*)src,
        (__attribute__((address_space(3))) void*)dst, 16, 0, 0);
}

// Stage a BK=64 bf16 tile (ROWS x 64 elems, 128B rows) from row-major global
// (element stride Kel, starting col k0) into LINEAR LDS via global_load_lds.
// Source address carries the inverse XOR swizzle; reads apply the same XOR.
template<int ROWS, int WAVES>
__device__ inline void stage64g(const unsigned short* __restrict__ g, size_t rowbase,
                                int Kel, int k0, unsigned short* lds, int w, int lane)
{
    constexpr int PER = (ROWS*128/1024) / WAVES;
    #pragma unroll
    for (int i = 0; i < PER; ++i) {
        const int inst = w + i*WAVES;                 // wave-uniform
        const unsigned o  = (unsigned)inst*1024u + (unsigned)lane*16u;
        const int      r  = (int)(o >> 7);
        const unsigned cb = o & 127u;
        const unsigned cs = cb ^ ((unsigned)(r & 7) << 4);
        gload16((const char*)(g + (rowbase + (size_t)r)*(size_t)Kel + k0) + cs,
                (char*)lds + (size_t)inst*1024u);
    }
}

// swizzled fragment read from a linear BK=64 tile
__device__ inline short8_t frag64(const unsigned short* lds, int r, int cb) {
    return *reinterpret_cast<const short8_t*>(
        (const char*)lds + (size_t)r*128 + (unsigned)(cb ^ ((r & 7) << 4)));
}

// swizzled 16B (8 cols) read from a BK=64 tile at column-byte cb (mult of 16)
__device__ inline us8 read8sw(const unsigned short* lds, int r, unsigned cb) {
    return *reinterpret_cast<const us8*>(
        (const char*)lds + (size_t)r*128 + (cb ^ ((unsigned)(r & 7) << 4)));
}

// 16-lane-group min (per DPP row); result in ALL lanes of each 16-group.
__device__ inline unsigned grp16_min_u32(unsigned v) {
    unsigned t;
    t = (unsigned)__builtin_amdgcn_update_dpp(-1, (int)v, 0xB1,  0xF, 0xF, false); v = t < v ? t : v; // quad_perm [1,0,3,2]
    t = (unsigned)__builtin_amdgcn_update_dpp(-1, (int)v, 0x4E,  0xF, 0xF, false); v = t < v ? t : v; // quad_perm [2,3,0,1]
    t = (unsigned)__builtin_amdgcn_update_dpp(-1, (int)v, 0x124, 0xF, 0xF, false); v = t < v ? t : v; // row_ror:4
    t = (unsigned)__builtin_amdgcn_update_dpp(-1, (int)v, 0x128, 0xF, 0xF, false); v = t < v ? t : v; // row_ror:8
    return v;
}

// 16-lane (DPP row) sum; result valid in lane 15 of each 16-lane row.
__device__ inline float dpp_rowsum16(float v) {
    float t;
    t = __uint_as_float((unsigned)__builtin_amdgcn_update_dpp(0, (int)__float_as_uint(v), 0x111, 0xF, 0xF, false)); v += t;
    t = __uint_as_float((unsigned)__builtin_amdgcn_update_dpp(0, (int)__float_as_uint(v), 0x112, 0xF, 0xF, false)); v += t;
    t = __uint_as_float((unsigned)__builtin_amdgcn_update_dpp(0, (int)__float_as_uint(v), 0x114, 0xF, 0xF, false)); v += t;
    t = __uint_as_float((unsigned)__builtin_amdgcn_update_dpp(0, (int)__float_as_uint(v), 0x118, 0xF, 0xF, false)); v += t;
    return v;
}

// counted-vmcnt barrier (T4): wait N outstanding VMEM, raw barrier, fence.
#define WAITB0  { asm volatile("s_waitcnt vmcnt(0)" ::: "memory");  __builtin_amdgcn_s_barrier(); asm volatile("" ::: "memory"); }
#define WAITB2  { asm volatile("s_waitcnt vmcnt(2)" ::: "memory");  __builtin_amdgcn_s_barrier(); asm volatile("" ::: "memory"); }
#define WAITB3  { asm volatile("s_waitcnt vmcnt(3)" ::: "memory");  __builtin_amdgcn_s_barrier(); asm volatile("" ::: "memory"); }
#define WAITB2L { asm volatile("s_waitcnt vmcnt(2) lgkmcnt(0)" ::: "memory"); __builtin_amdgcn_s_barrier(); asm volatile("" ::: "memory"); }

// ---------------------------------------------------------------------------
// bf16 MFMA GEMM, BK=64, global_load_lds staging. (head only now)
// ---------------------------------------------------------------------------
template<int ACT, bool RES, bool MASK, bool OUTF, bool OUTB, bool OUTS>
__global__ __launch_bounds__(256)
void bgemm_k(const unsigned short* __restrict__ A,
             const unsigned short* __restrict__ W,
             const float* __restrict__ bias,
             const float* __restrict__ resp,
             const int* __restrict__ mask,
             float* __restrict__ Cf, unsigned short* __restrict__ Cb,
             unsigned short* Ohi, unsigned short* Olo,
             int M, int N, int K)
{
    __shared__ __align__(16) unsigned short As[128*64];
    __shared__ __align__(16) unsigned short Bs[128*64];

    const int tid  = threadIdx.x;
    const int lane = tid & 63;
    const int w    = tid >> 6;
    const int wr   = w >> 1, wc = w & 1;
    const int row0 = blockIdx.x * 128;
    const int col0 = blockIdx.y * 128;
    const int l15  = lane & 15;
    const int ko   = lane >> 4;

    f32x4 acc[4][4];
    #pragma unroll
    for (int m = 0; m < 4; ++m)
        #pragma unroll
        for (int n = 0; n < 4; ++n) acc[m][n] = (f32x4){0.f,0.f,0.f,0.f};

    for (int k0 = 0; k0 < K; k0 += 64) {
        stage64g<128,4>(A, (size_t)row0, K, k0, As, w, lane);
        stage64g<128,4>(W, (size_t)col0, K, k0, Bs, w, lane);
        __syncthreads();
        #pragma unroll
        for (int ks = 0; ks < 2; ++ks) {
            short8_t aF[4], bF[4];
            #pragma unroll
            for (int m = 0; m < 4; ++m)
                aF[m] = frag64(As, wr*64 + m*16 + l15, ks*64 + ko*16);
            #pragma unroll
            for (int n = 0; n < 4; ++n)
                bF[n] = frag64(Bs, wc*64 + n*16 + l15, ks*64 + ko*16);
            #pragma unroll
            for (int m = 0; m < 4; ++m)
                #pragma unroll
                for (int n = 0; n < 4; ++n)
                    acc[m][n] = __builtin_amdgcn_mfma_f32_16x16x32_bf16(aF[m], bF[n], acc[m][n], 0, 0, 0);
        }
        __syncthreads();
    }

    #pragma unroll
    for (int m = 0; m < 4; ++m) {
        const int rbase = row0 + wr*64 + m*16 + ko*4;
        #pragma unroll
        for (int n = 0; n < 4; ++n) {
            const int col = col0 + wc*64 + n*16 + l15;
            const float bv = bias[col];
            #pragma unroll
            for (int r = 0; r < 4; ++r) {
                const int row = rbase + r;
                float v = acc[m][n][r] + bv;
                if constexpr (ACT == ACT_LRELU) v = LRELU_(v);
                if constexpr (RES)  v += resp[(size_t)row*N + col];
                if constexpr (MASK) v *= (mask[row] != 0) ? 1.f : 0.f;
                if constexpr (OUTF) Cf[(size_t)row*N + col] = v;
                if constexpr (OUTB) Cb[(size_t)row*N + col] = f2bf(v);
                if constexpr (OUTS) {
                    unsigned short h = f2bf(v);
                    Ohi[(size_t)row*N + col] = h;
                    Olo[(size_t)row*N + col] = f2bf(v - bf2f(h));
                }
            }
        }
    }
}

// ---------------------------------------------------------------------------
// bf16 MFMA GEMM fused with full-row LayerNorm epilogue (BK=64).
// MODE 1: bf16 out. MODE 2: split hi/lo ONLY (no fp32).
// ---------------------------------------------------------------------------
template<int WR, int WC, bool DO_LRELU, bool MASKMUL, int MODE, bool AF32>
__global__ __launch_bounds__(WR*WC*64)
void bgemm_ln_k(const void* __restrict__ Ap,
                const unsigned short* __restrict__ W,
                const float* __restrict__ bias,
                const float* __restrict__ gam,
                const float* __restrict__ bet,
                const int* __restrict__ mask,
                void* __restrict__ outv,
                unsigned short* __restrict__ ohi, unsigned short* __restrict__ olo,
                int K)
{
    constexpr int BM = WR*64;
    constexpr int BN = WC*64;
    constexpr int THREADS = WR*WC*64;
    constexpr int WAVES = THREADS/64;
    __shared__ __align__(16) unsigned short As[BM*64];
    __shared__ __align__(16) unsigned short Bs[BN*64];
    __shared__ float red_s[WC][BM];
    __shared__ float red_q[WC][BM];
    __shared__ float mu_l[BM];
    __shared__ float rs_l[BM];

    const int tid  = threadIdx.x;
    const int lane = tid & 63;
    const int w    = tid >> 6;
    const int wr   = w / WC, wc = w % WC;
    const int row0 = blockIdx.x * BM;
    const int l15  = lane & 15;
    const int ko   = lane >> 4;

    f32x4 acc[4][4];
    #pragma unroll
    for (int m = 0; m < 4; ++m)
        #pragma unroll
        for (int n = 0; n < 4; ++n) acc[m][n] = (f32x4){0.f,0.f,0.f,0.f};

    for (int k0 = 0; k0 < K; k0 += 64) {
        if constexpr (AF32) {
            const float* Af = (const float*)Ap;
            constexpr int CH = (BM*8)/THREADS;    // 16B chunks per thread
            #pragma unroll
            for (int i = 0; i < CH; ++i) {
                const int q = i*THREADS + tid;
                const unsigned o  = (unsigned)q*16u;
                const int      r  = (int)(o >> 7);
                const unsigned cb = o & 127u;
                const unsigned cs = cb ^ ((unsigned)(r & 7) << 4);
                const float* src = Af + (size_t)(row0 + r)*K + k0 + (cs >> 1);
                const float4 f0 = *reinterpret_cast<const float4*>(src);
                const float4 f1 = *reinterpret_cast<const float4*>(src + 4);
                short8_t v;
                v[0]=(short)f2bf(f0.x); v[1]=(short)f2bf(f0.y); v[2]=(short)f2bf(f0.z); v[3]=(short)f2bf(f0.w);
                v[4]=(short)f2bf(f1.x); v[5]=(short)f2bf(f1.y); v[6]=(short)f2bf(f1.z); v[7]=(short)f2bf(f1.w);
                *reinterpret_cast<short8_t*>((char*)As + o) = v;
            }
        } else {
            stage64g<BM,WAVES>((const unsigned short*)Ap, (size_t)row0, K, k0, As, w, lane);
        }
        stage64g<BN,WAVES>(W, 0, K, k0, Bs, w, lane);
        __syncthreads();
        #pragma unroll
        for (int ks = 0; ks < 2; ++ks) {
            short8_t aF[4], bF[4];
            #pragma unroll
            for (int m = 0; m < 4; ++m)
                aF[m] = frag64(As, wr*64 + m*16 + l15, ks*64 + ko*16);
            #pragma unroll
            for (int n = 0; n < 4; ++n)
                bF[n] = frag64(Bs, wc*64 + n*16 + l15, ks*64 + ko*16);
            #pragma unroll
            for (int m = 0; m < 4; ++m)
                #pragma unroll
                for (int n = 0; n < 4; ++n)
                    acc[m][n] = __builtin_amdgcn_mfma_f32_16x16x32_bf16(aF[m], bF[n], acc[m][n], 0, 0, 0);
        }
        __syncthreads();
    }

    float bv[4];
    #pragma unroll
    for (int n = 0; n < 4; ++n) bv[n] = bias[wc*64 + n*16 + l15];
    #pragma unroll
    for (int m = 0; m < 4; ++m)
        #pragma unroll
        for (int n = 0; n < 4; ++n)
            #pragma unroll
            for (int r = 0; r < 4; ++r) acc[m][n][r] += bv[n];

    #pragma unroll
    for (int m = 0; m < 4; ++m) {
        #pragma unroll
        for (int r = 0; r < 4; ++r) {
            float s = acc[m][0][r] + acc[m][1][r] + acc[m][2][r] + acc[m][3][r];
            float q = acc[m][0][r]*acc[m][0][r] + acc[m][1][r]*acc[m][1][r]
                    + acc[m][2][r]*acc[m][2][r] + acc[m][3][r]*acc[m][3][r];
            s = dpp_rowsum16(s);
            q = dpp_rowsum16(q);
            if (l15 == 15) {
                int rl = wr*64 + m*16 + ko*4 + r;
                red_s[wc][rl] = s;
                red_q[wc][rl] = q;
            }
        }
    }
    __syncthreads();
    if (tid < BM) {
        float s = 0.f, q = 0.f;
        #pragma unroll
        for (int c2 = 0; c2 < WC; ++c2) { s += red_s[c2][tid]; q += red_q[c2][tid]; }
        float mu  = s * (1.0f/BN);
        float var = q * (1.0f/BN) - mu*mu;
        mu_l[tid] = mu;
        rs_l[tid] = rsqrtf(fmaxf(var, 0.f) + 1e-5f);
    }
    __syncthreads();

    float gm[4], bt[4];
    #pragma unroll
    for (int n = 0; n < 4; ++n) {
        int col = wc*64 + n*16 + l15;
        gm[n] = gam[col]; bt[n] = bet[col];
    }
    #pragma unroll
    for (int m = 0; m < 4; ++m) {
        #pragma unroll
        for (int r = 0; r < 4; ++r) {
            const int rl  = wr*64 + m*16 + ko*4 + r;
            const int row = row0 + rl;
            const float mu = mu_l[rl], rs = rs_l[rl];
            float mf = 1.f;
            if constexpr (MASKMUL) mf = (mask[row] != 0) ? 1.f : 0.f;
            #pragma unroll
            for (int n = 0; n < 4; ++n) {
                const int col = wc*64 + n*16 + l15;
                float y = (acc[m][n][r] - mu) * rs * gm[n] + bt[n];
                if constexpr (DO_LRELU) y = LRELU_(y);
                if constexpr (MASKMUL)  y *= mf;
                if constexpr (MODE == 1) {
                    ((unsigned short*)outv)[(size_t)row*BN + col] = f2bf(y);
                } else {
                    unsigned short h = f2bf(y);
                    ohi[(size_t)row*BN + col] = h;
                    olo[(size_t)row*BN + col] = f2bf(y - bf2f(h));
                }
            }
        }
    }
}

// ---------------------------------------------------------------------------
// MEGA: fc1 + distance + top-9 + gather, ONE block per batch (1024 thr).
// Split-format gather; neighbor max as fmax(sum) then single subtract
// (bit-identical by monotone rounding). Top-k skipped when all 4 wave-slot
// rows masked.
// ---------------------------------------------------------------------------
__global__ __launch_bounds__(1024)
void fc1_dist_topk_gather_k(const unsigned short* __restrict__ xhi,
                            const unsigned short* __restrict__ xlo,
                            const unsigned short* __restrict__ Whi,  // [128][128]
                            const unsigned short* __restrict__ Wlo,  // [128][128]
                            const float* __restrict__ fc1b,
                            const int* __restrict__ mask,
                            unsigned short* __restrict__ cat)
{
    __shared__ __align__(16) unsigned short BUF[4][NNODE*64];   // 128KB: hi kt0,kt1, lo kt0,kt1
    __shared__ __align__(16) unsigned short Ws[128*64];         // 16KB weight tile
    __shared__ float x2s[NNODE];
    __shared__ unsigned char idx_s[NNODE*KNN];
    __shared__ unsigned char msk_s[NNODE];

    const int b    = blockIdx.x;
    const int tid  = threadIdx.x;
    const int lane = tid & 63;
    const int w    = tid >> 6;          // 0..15
    const int l15  = lane & 15;
    const int g    = lane >> 4;         // 0..3

    const unsigned short* Xhi = xhi + (size_t)b*NNODE*DD;
    const unsigned short* Xlo = xlo + (size_t)b*NNODE*DD;
    const int* mkb = mask + b*NNODE;

    // ---- stage x split (both k-tiles) ----
    stage64g<NNODE,16>(Xhi, 0, DD, 0,  &BUF[0][0], w, lane);
    stage64g<NNODE,16>(Xhi, 0, DD, 64, &BUF[1][0], w, lane);
    stage64g<NNODE,16>(Xlo, 0, DD, 0,  &BUF[2][0], w, lane);
    stage64g<NNODE,16>(Xlo, 0, DD, 64, &BUF[3][0], w, lane);
    if (tid < NNODE) msk_s[tid] = (mkb[tid] != 0) ? 1 : 0;
    __syncthreads();

    const int arow = w*16 + l15;        // 0..255

    // ---- fc1: h = x @ W^T + b, 3 split phases; weights streamed ----
    f32x4 hacc[8];
    #pragma unroll
    for (int n = 0; n < 8; ++n) hacc[n] = (f32x4){0.f,0.f,0.f,0.f};

    #pragma unroll
    for (int wp = 0; wp < 4; ++wp) {                 // (Whi,kt0)(Whi,kt1)(Wlo,kt0)(Wlo,kt1)
        const unsigned short* Wsrc = (wp < 2) ? Whi : Wlo;
        const int kt = wp & 1;
        stage64g<128,16>(Wsrc, 0, DD, kt*64, Ws, w, lane);
        __syncthreads();
        const int nAv = (wp < 2) ? 2 : 1;            // Whi: x_hi + x_lo; Wlo: x_hi only
        for (int av = 0; av < nAv; ++av) {
            const unsigned short* At = (av == 0) ? &BUF[kt][0] : &BUF[2+kt][0];
            #pragma unroll
            for (int ks = 0; ks < 2; ++ks) {
                short8_t aF = frag64(At, arow, ks*64 + g*16);
                #pragma unroll
                for (int n = 0; n < 8; ++n) {
                    short8_t bF = frag64(Ws, n*16 + l15, ks*64 + g*16);
                    hacc[n] = __builtin_amdgcn_mfma_f32_16x16x32_bf16(aF, bF, hacc[n], 0, 0, 0);
                }
            }
        }
        __syncthreads();                             // Ws reads + (last) x reads done
    }

    // ---- bias + split + x2; write h into BUF (x is dead) ----
    {
        float qr[4] = {0.f, 0.f, 0.f, 0.f};
        #pragma unroll
        for (int n = 0; n < 8; ++n) {
            const int col = n*16 + l15;
            const float bv = fc1b[col];
            const int kt = col >> 6;
            const unsigned bc = (unsigned)((col & 63) * 2);
            #pragma unroll
            for (int r = 0; r < 4; ++r) {
                const int row = w*16 + g*4 + r;
                float v = hacc[n][r] + bv;
                unsigned short hh = f2bf(v);
                unsigned short hl = f2bf(v - bf2f(hh));
                const unsigned off = (unsigned)(row*128) + (bc ^ ((unsigned)(row & 7) << 4));
                *(unsigned short*)((char*)&BUF[kt][0]   + off) = hh;
                *(unsigned short*)((char*)&BUF[2+kt][0] + off) = hl;
                float vv = bf2f(hh) + bf2f(hl);
                qr[r] += vv*vv;
            }
        }
        #pragma unroll
        for (int r = 0; r < 4; ++r) {
            float q = dpp_rowsum16(qr[r]);
            if (l15 == 15) x2s[w*16 + g*4 + r] = q;
        }
    }
    __syncthreads();

    // ---- distance MFMA (h resident) ----
    f32x4 acc[16];
    #pragma unroll
    for (int n = 0; n < 16; ++n) acc[n] = (f32x4){0.f,0.f,0.f,0.f};

    __builtin_amdgcn_s_setprio(1);
    #pragma unroll
    for (int kt = 0; kt < 2; ++kt) {
        #pragma unroll
        for (int ks = 0; ks < 2; ++ks) {
            short8_t aH = frag64(&BUF[kt][0],   arow, ks*64 + g*16);
            short8_t aL = frag64(&BUF[2+kt][0], arow, ks*64 + g*16);
            #pragma unroll
            for (int n = 0; n < 16; ++n) {
                int brow = n*16 + l15;
                short8_t bH = frag64(&BUF[kt][0],   brow, ks*64 + g*16);
                short8_t bL = frag64(&BUF[2+kt][0], brow, ks*64 + g*16);
                acc[n] = __builtin_amdgcn_mfma_f32_16x16x32_bf16(aH, bH, acc[n], 0, 0, 0); // hi.hi
                acc[n] = __builtin_amdgcn_mfma_f32_16x16x32_bf16(aL, bH, acc[n], 0, 0, 0); // lo.hi
                acc[n] = __builtin_amdgcn_mfma_f32_16x16x32_bf16(aH, bL, acc[n], 0, 0, 0); // hi.lo
            }
        }
    }
    __builtin_amdgcn_s_setprio(0);

    float x2c[16]; unsigned mk[16];
    #pragma unroll
    for (int n = 0; n < 16; ++n) {
        int col = n*16 + l15;
        x2c[n] = x2s[col];
        mk[n]  = (unsigned)msk_s[col];
    }

    #pragma unroll
    for (int r = 0; r < 4; ++r) {
        const int rb = w*16 + r;
        if ((msk_s[rb] | msk_s[rb+4] | msk_s[rb+8] | msk_s[rb+12]) == 0) continue;
        const int lrow = w*16 + g*4 + r;          // this wave's rows only
        const float x2r = x2s[lrow];
        unsigned key[16];
        #pragma unroll
        for (int n = 0; n < 16; ++n) {
            float v = x2r + x2c[n] - 2.0f*acc[n][r];
            if (!mk[n]) v = 1e10f;
            unsigned u = __float_as_uint(v);
            u = (u & 0x80000000u) ? ~u : (u | 0x80000000u);
            key[n] = (u & 0xFFFFFF00u) | (unsigned)(n*16 + l15);
        }
        for (int it = 0; it < KNN; ++it) {
            unsigned a0 = key[0]  < key[1]  ? key[0]  : key[1];
            unsigned a1 = key[2]  < key[3]  ? key[2]  : key[3];
            unsigned a2 = key[4]  < key[5]  ? key[4]  : key[5];
            unsigned a3 = key[6]  < key[7]  ? key[6]  : key[7];
            unsigned a4 = key[8]  < key[9]  ? key[8]  : key[9];
            unsigned a5 = key[10] < key[11] ? key[10] : key[11];
            unsigned a6 = key[12] < key[13] ? key[12] : key[13];
            unsigned a7 = key[14] < key[15] ? key[14] : key[15];
            unsigned b0 = a0 < a1 ? a0 : a1;
            unsigned b1 = a2 < a3 ? a2 : a3;
            unsigned b2 = a4 < a5 ? a4 : a5;
            unsigned b3 = a6 < a7 ? a6 : a7;
            unsigned c0 = b0 < b1 ? b0 : b1;
            unsigned c1 = b2 < b3 ? b2 : b3;
            unsigned lmin = c0 < c1 ? c0 : c1;
            unsigned gmin = grp16_min_u32(lmin);
            if (l15 == 0) idx_s[lrow*KNN + it] = (unsigned char)(gmin & 0xFFu);
            #pragma unroll
            for (int n = 0; n < 16; ++n)
                if (key[n] == gmin) key[n] = 0xFFFFFFFFu;
        }
    }
    // NO block barrier: gather touches only this wave's rows (same-wave DS order).

    const int gi = lane & 7;                       // granule 0..7 (8 cols)
    const unsigned cb = (unsigned)(gi * 16);       // byte col within tile
    #pragma unroll
    for (int kt = 0; kt < 2; ++kt) {
        #pragma unroll
        for (int p = 0; p < 2; ++p) {
            const int rl = w*16 + p*8 + (lane >> 3);   // this wave's row
            us8 h8 = read8sw(&BUF[kt][0],   rl, cb);
            us8 l8 = read8sw(&BUF[2+kt][0], rl, cb);
            float hi[8], m[8];
            #pragma unroll
            for (int d = 0; d < 8; ++d) { hi[d] = bf2f(h8[d]) + bf2f(l8[d]); m[d] = -1e9f; }
            bool any = false;
            #pragma unroll
            for (int q = 0; q < KNN; ++q) {
                int j = idx_s[rl*KNN + q];
                if (msk_s[j]) {
                    any = true;
                    us8 a = read8sw(&BUF[kt][0],   j, cb);
                    us8 o = read8sw(&BUF[2+kt][0], j, cb);
                    #pragma unroll
                    for (int d = 0; d < 8; ++d)
                        m[d] = fmaxf(m[d], bf2f(a[d]) + bf2f(o[d]));   // sub deferred
                }
            }
            us8 o1, o2;
            #pragma unroll
            for (int d = 0; d < 8; ++d) {
                o1[d] = f2bf(hi[d]);
                o2[d] = any ? f2bf(m[d] - hi[d]) : (unsigned short)0;
            }
            const size_t rowbase = (size_t)(b*NNODE + rl)*(2*DD);
            const int c0 = kt*64 + gi*8;
            *reinterpret_cast<us8*>(&cat[rowbase + c0])      = o1;
            *reinterpret_cast<us8*>(&cat[rowbase + DD + c0]) = o2;
        }
    }
}

// ---------------------------------------------------------------------------
// Fused conv + fc2 + FFN, BM=64, 512 threads (8 waves x 16 cols each).
// 80KB LDS -> 2 blocks/CU, 4 waves/SIMD. Ring-3 weight staging, counted
// vmcnt (2-instr stages), setprio. Epilogue also writes per-block column
// partial sums (pool fusion): gpart[blockIdx][col] = sum over 64 rows.
// ---------------------------------------------------------------------------
__global__ __launch_bounds__(512, 4)
void conv_ffn_k(const unsigned short* __restrict__ cat,
                const unsigned short* __restrict__ Wc,   // [128][256]
                const float* __restrict__ cb,
                const unsigned short* __restrict__ W2c,  // [128][128] (fc2)
                const float* __restrict__ fb,
                const unsigned short* __restrict__ W1,   // [512][128] (ffn1)
                const float* __restrict__ b1,
                const unsigned short* __restrict__ W2f,  // [128][512] (ffn2)
                const float* __restrict__ b2,
                const int* __restrict__ mask,
                unsigned short* xhi,                     // in: x residual / out: new x
                unsigned short* xlo,
                float* __restrict__ gpart)               // [1024][128] col partials
{
    __shared__ __align__(16) unsigned short Bs[3][128*64];   // 48KB ring
    __shared__ __align__(16) unsigned short h2s[2][64*64];   // 16KB
    __shared__ __align__(16) unsigned short Xs[2][64*64];    // 16KB; conv A-tiles alias

    const int tid  = threadIdx.x;
    const int lane = tid & 63;
    const int w    = tid >> 6;      // 0..7: wave col group (cols w*16..w*16+15)
    const int row0 = blockIdx.x * 64;
    const int l15  = lane & 15;
    const int ko   = lane >> 4;

    // tile t -> weight source (t = 0..21); 2 VMEM instr per wave each
    auto issueB = [&](int t) {
        unsigned short* buf = &Bs[t % 3][0];
        if (t < 4)      stage64g<128,8>(Wc,  0, 256, t*64, buf, w, lane);
        else if (t < 6) stage64g<128,8>(W2c, 0, 128, (t-4)*64, buf, w, lane);
        else {
            int c = (t-6) >> 2, j = (t-6) & 3;
            if (j < 2) stage64g<128,8>(W1, (size_t)(c*128), DD, j*64, buf, w, lane);
            else       stage64g<128,8>(W2f, 0, FFND, c*128 + (j-2)*64, buf, w, lane);
        }
    };

    #define MM8(ATILE, BTILE, ACC)                                              \
        { __builtin_amdgcn_s_setprio(1);                                        \
          _Pragma("unroll")                                                     \
          for (int ks = 0; ks < 2; ++ks) {                                      \
            short8_t aF[4], bF;                                                 \
            _Pragma("unroll")                                                   \
            for (int m = 0; m < 4; ++m) aF[m] = frag64(ATILE, m*16 + l15, ks*64 + ko*16); \
            bF = frag64(BTILE, w*16 + l15, ks*64 + ko*16);                      \
            _Pragma("unroll")                                                   \
            for (int m = 0; m < 4; ++m)                                         \
              ACC[m] = __builtin_amdgcn_mfma_f32_16x16x32_bf16(aF[m], bF, ACC[m], 0, 0, 0); } \
          __builtin_amdgcn_s_setprio(0); }

    #define H2WRITE(ACC, BPTR, DST)                                             \
        { const int kt_ = w >> 2;                                               \
          const int col_ = w*16 + l15;                                          \
          const float bv_ = (BPTR)[col_];                                       \
          const unsigned bc_ = (unsigned)(((w & 3)*16 + l15) * 2);              \
          _Pragma("unroll")                                                     \
          for (int m = 0; m < 4; ++m)                                           \
            _Pragma("unroll")                                                   \
            for (int r = 0; r < 4; ++r) {                                       \
              const int row_ = m*16 + ko*4 + r;                                 \
              float v_ = LRELU_(ACC[m][r] + bv_);                               \
              *(unsigned short*)((char*)&(DST)[kt_][0] + row_*128               \
                  + (bc_ ^ ((unsigned)(row_ & 7) << 4))) = f2bf(v_); } }

    // ---- prologue (issue order: Xs0(1), B0(2), Xs1(1), B1(2) -> 6 out) ----
    stage64g<64,8>(cat, (size_t)row0, 256, 0,  &Xs[0][0], w, lane);
    issueB(0);
    stage64g<64,8>(cat, (size_t)row0, 256, 64, &Xs[1][0], w, lane);
    issueB(1);

    // ---- conv phases P0..P3 ----
    f32x4 accc[4];
    #pragma unroll
    for (int m = 0; m < 4; ++m) accc[m] = (f32x4){0.f,0.f,0.f,0.f};

    WAITB3;                                    // P0: need Xs0+B0 (Xs1+B1 = 3 out)
    issueB(2);
    MM8(&Xs[0][0], &Bs[0][0], accc);

    WAITB2;                                    // P1: need Xs1+B1 (B2 = 2 out)
    stage64g<64,8>(cat, (size_t)row0, 256, 128, &Xs[0][0], w, lane);
    issueB(3);
    MM8(&Xs[1][0], &Bs[1][0], accc);

    WAITB2;                                    // P2: need B2+cat2 (B3 = 2 out)
    stage64g<64,8>(cat, (size_t)row0, 256, 192, &Xs[1][0], w, lane);
    issueB(4);
    MM8(&Xs[0][0], &Bs[2][0], accc);

    WAITB2;                                    // P3: need B3+cat3 (B4 = 2 out)
    issueB(5);
    MM8(&Xs[1][0], &Bs[0][0], accc);
    H2WRITE(accc, cb, h2s);

    // ---- fc2 phases P4..P5 ----
    f32x4 accx[4];
    #pragma unroll
    for (int m = 0; m < 4; ++m) accx[m] = (f32x4){0.f,0.f,0.f,0.f};

    WAITB2L;                                   // P4: need B4 + h2s writes
    issueB(6);
    MM8(&h2s[0][0], &Bs[1][0], accx);

    WAITB2;                                    // P5: need B5 (B6 = 2 out)
    issueB(7);
    MM8(&h2s[1][0], &Bs[2][0], accx);
    float xn[4][4];
    {
        const int kt = w >> 2;
        const int col = w*16 + l15;
        const float bv = fb[col];
        const unsigned bc = (unsigned)(((w & 3)*16 + l15) * 2);
        #pragma unroll
        for (int m = 0; m < 4; ++m) {
            #pragma unroll
            for (int r = 0; r < 4; ++r) {
                const int row = m*16 + ko*4 + r;
                const size_t gix = (size_t)(row0 + row)*DD + col;
                float res = bf2f(xhi[gix]) + bf2f(xlo[gix]);
                float v = accx[m][r] + bv + res;
                xn[m][r] = v;
                *(unsigned short*)((char*)&Xs[kt][0] + row*128
                    + (bc ^ ((unsigned)(row & 7) << 4))) = f2bf(v);
            }
        }
    }

    // ---- FFN chunks, phases P6..P21 ----
    f32x4 acc2[4];
    #pragma unroll
    for (int m = 0; m < 4; ++m) acc2[m] = (f32x4){0.f,0.f,0.f,0.f};

    #pragma unroll
    for (int c = 0; c < 4; ++c) {
        const int tb = 6 + c*4;
        f32x4 acc1[4];
        #pragma unroll
        for (int m = 0; m < 4; ++m) acc1[m] = (f32x4){0.f,0.f,0.f,0.f};

        if (c == 0) { WAITB2L; } else { WAITB2; }
        if (tb+2 <= 21) issueB(tb+2);
        MM8(&Xs[0][0], &Bs[tb % 3][0], acc1);

        WAITB2;
        if (tb+3 <= 21) issueB(tb+3);
        MM8(&Xs[1][0], &Bs[(tb+1) % 3][0], acc1);
        H2WRITE(acc1, b1 + c*128, h2s);

        WAITB2L;
        if (tb+4 <= 21) issueB(tb+4);
        MM8(&h2s[0][0], &Bs[(tb+2) % 3][0], acc2);

        if (c == 3) { WAITB0; } else { WAITB2; }
        if (tb+5 <= 21) issueB(tb+5);
        MM8(&h2s[1][0], &Bs[(tb+3) % 3][0], acc2);
    }

    // ---- epilogue: x = acc2 + b2 + xn, masked; write split + pool partial ----
    {
        const int col = w*16 + l15;
        const float bv = b2[col];
        float psum = 0.f;
        #pragma unroll
        for (int m = 0; m < 4; ++m) {
            const int rbase = row0 + m*16 + ko*4;
            #pragma unroll
            for (int r = 0; r < 4; ++r) {
                const int row = rbase + r;
                float v = acc2[m][r] + bv + xn[m][r];
                v *= (mask[row] != 0) ? 1.f : 0.f;
                psum += v;
                unsigned short h = f2bf(v);
                xhi[(size_t)row*DD + col] = h;
                xlo[(size_t)row*DD + col] = f2bf(v - bf2f(h));
            }
        }
        // reduce the 4 ko-threads sharing this col (lanes differ in bits 4..5)
        psum += __shfl_xor(psum, 16);
        psum += __shfl_xor(psum, 32);
        if (ko == 0) gpart[(size_t)blockIdx.x*DD + col] = psum;
    }
    #undef MM8
    #undef H2WRITE
}

// pool from per-block partials (4 per batch) — no 33.5MB re-read.
__global__ __launch_bounds__(128)
void pool_k(const float* __restrict__ gpart, const int* __restrict__ mask,
            float* __restrict__ g, unsigned short* __restrict__ gbf)
{
    const int b = blockIdx.x, c = threadIdx.x;
    float s = gpart[(size_t)(b*4 + 0)*DD + c] + gpart[(size_t)(b*4 + 1)*DD + c]
            + gpart[(size_t)(b*4 + 2)*DD + c] + gpart[(size_t)(b*4 + 3)*DD + c];
    int cnt = 0;
    for (int n = 0; n < NNODE; ++n) cnt += (mask[b*NNODE + n] != 0) ? 1 : 0;
    float v = s / fmaxf((float)cnt, 1.0f);
    g[b*DD + c] = v;
    gbf[b*DD + c] = f2bf(v);
}

// ---------------------------------------------------------------------------
// All weight transpose-casts in ONE kernel (compile-time job table).
// ---------------------------------------------------------------------------
__global__ __launch_bounds__(256)
void prep_all_k(const float* __restrict__ emb_w1, const float* __restrict__ emb_w2,
                const float* __restrict__ conv_w, const float* __restrict__ fc2_w,
                const float* __restrict__ f1_w,   const float* __restrict__ f2_w,
                const float* __restrict__ fc1_w,  const float* __restrict__ ow1,
                const float* __restrict__ ow2,
                unsigned short* __restrict__ emb_w1t, unsigned short* __restrict__ emb_w2t,
                unsigned short* __restrict__ conv_wt, unsigned short* __restrict__ fc2_wt,
                unsigned short* __restrict__ ffn1_wt, unsigned short* __restrict__ ffn2_wt,
                unsigned short* __restrict__ fc1_wthi, unsigned short* __restrict__ fc1_wtlo,
                unsigned short* __restrict__ ow1t, unsigned short* __restrict__ ow2t)
{
    __shared__ float tile[32][33];
    const int tx = threadIdx.x & 31, ty = threadIdx.x >> 5;

    int bid = blockIdx.x;
    const float* src = nullptr; unsigned short* dst = nullptr; unsigned short* dlo = nullptr;
    int K = 0, N = 0;
    do {
        if (bid < 16)  { src = emb_w1; dst = emb_w1t; K = 64;  N = 256; break; }  bid -= 16;
        if (bid < 32)  { src = emb_w2; dst = emb_w2t; K = 256; N = 128; break; }  bid -= 32;
        if (bid < 64)  { int l = bid >> 5; bid &= 31;
                         src = conv_w + (size_t)l*256*128; dst = conv_wt + (size_t)l*128*256;
                         K = 256; N = 128; break; }                               bid -= 64;
        if (bid < 32)  { int l = bid >> 4; bid &= 15;
                         src = fc2_w + (size_t)l*128*128; dst = fc2_wt + (size_t)l*128*128;
                         K = 128; N = 128; break; }                               bid -= 32;
        if (bid < 128) { int l = bid >> 6; bid &= 63;
                         src = f1_w + (size_t)l*128*512; dst = ffn1_wt + (size_t)l*512*128;
                         K = 128; N = 512; break; }                               bid -= 128;
        if (bid < 128) { int l = bid >> 6; bid &= 63;
                         src = f2_w + (size_t)l*512*128; dst = ffn2_wt + (size_t)l*128*512;
                         K = 512; N = 128; break; }                               bid -= 128;
        if (bid < 32)  { int l = bid >> 4; bid &= 15;
                         src = fc1_w + (size_t)l*128*128;
                         dst = fc1_wthi + (size_t)l*128*128; dlo = fc1_wtlo + (size_t)l*128*128;
                         K = 128; N = 128; break; }                               bid -= 32;
        if (bid < 64)  { src = ow1; dst = ow1t; K = 128; N = 512; break; }        bid -= 64;
        { src = ow2; dst = ow2t; K = 512; N = 2048; }
    } while (0);

    const int nbx = N / 32;
    const int bx = bid % nbx, by = bid / nbx;
    const int k0 = by*32, n0 = bx*32;

    #pragma unroll
    for (int i = ty; i < 32; i += 8)
        tile[i][tx] = src[(size_t)(k0+i)*N + n0+tx];
    __syncthreads();
    #pragma unroll
    for (int i = ty; i < 32; i += 8) {
        float v = tile[tx][i];
        unsigned short h = f2bf(v);
        dst[(size_t)(n0+i)*K + k0+tx] = h;
        if (dlo) dlo[(size_t)(n0+i)*K + k0+tx] = f2bf(v - bf2f(h));
    }
}

// ---------------------------------------------------------------------------
extern "C" void kernel_launch(void* const* d_in, const int* in_sizes, int n_in,
                              void* d_out, int out_size, void* d_ws, size_t ws_size,
                              hipStream_t stream)
{
    const float* nodes  = (const float*)d_in[0];
    const int*   maskp  = (const int*)  d_in[1];
    const float* emb_w1 = (const float*)d_in[2];
    const float* emb_b1 = (const float*)d_in[3];
    const float* ln1_g  = (const float*)d_in[4];
    const float* ln1_b  = (const float*)d_in[5];
    const float* emb_w2 = (const float*)d_in[6];
    const float* emb_b2 = (const float*)d_in[7];
    const float* ln2_g  = (const float*)d_in[8];
    const float* ln2_b  = (const float*)d_in[9];
    const float* fc1_w  = (const float*)d_in[10];
    const float* fc1_b  = (const float*)d_in[11];
    const float* conv_w = (const float*)d_in[12];
    const float* conv_b = (const float*)d_in[13];
    const float* fc2_w  = (const float*)d_in[14];
    const float* fc2_b  = (const float*)d_in[15];
    const float* f1_w   = (const float*)d_in[16];
    const float* f1_b   = (const float*)d_in[17];
    const float* f2_w   = (const float*)d_in[18];
    const float* f2_b   = (const float*)d_in[19];
    const float* ow1    = (const float*)d_in[20];
    const float* ob1    = (const float*)d_in[21];
    const float* ow2    = (const float*)d_in[22];
    const float* ob2    = (const float*)d_in[23];
    float* out = (float*)d_out;

    // ---- workspace layout ----
    char* base = (char*)d_ws;
    char*  H   = base + (size_t)BNROWS*DD*4;            // x_hi/x_lo (residual-carrying)
    char*  BIG = H + (size_t)BNROWS*DD*4;               // cat [0:33.5M]
    float*          g     = (float*)(BIG + (size_t)BNROWS*2*DD*4);
    unsigned short* g_bf  = (unsigned short*)(g + BB*DD);
    unsigned short* hid2_bf = g_bf + BB*DD;
    unsigned short* wbuf  = hid2_bf + BB*FFND;

    unsigned short* x_hi   = (unsigned short*)H;
    unsigned short* x_lo   = x_hi + (size_t)BNROWS*DD;
    unsigned short* t256_bf= (unsigned short*)base;     // embed phase scratch
    unsigned short* cat_bf = (unsigned short*)BIG;

    unsigned short* emb_w1t  = wbuf;
    unsigned short* emb_w2t  = emb_w1t + 256*64;
    unsigned short* conv_wt  = emb_w2t + 128*256;
    unsigned short* fc2_wt   = conv_wt + 2*128*256;
    unsigned short* ffn1_wt  = fc2_wt  + 2*128*128;
    unsigned short* ffn2_wt  = ffn1_wt + 2*512*128;
    unsigned short* fc1_wthi = ffn2_wt + 2*128*512;
    unsigned short* fc1_wtlo = fc1_wthi + 2*128*128;
    unsigned short* ow1t     = fc1_wtlo + 2*128*128;
    unsigned short* ow2t     = ow1t + 512*128;
    float*          gpart    = (float*)(ow2t + 512*2048);   // [1024][128] pool partials

    const dim3 blk(256);

    // ---- all weight transpose-casts (one launch) ----
    prep_all_k<<<1520, blk, 0, stream>>>(
        emb_w1, emb_w2, conv_w, fc2_w, f1_w, f2_w, fc1_w, ow1, ow2,
        emb_w1t, emb_w2t, conv_wt, fc2_wt, ffn1_wt, ffn2_wt,
        fc1_wthi, fc1_wtlo, ow1t, ow2t);

    // ---- Embedding (GEMM + fused LN) ----
    bgemm_ln_k<2,4,true,false,1,true>
        <<<dim3(BNROWS/128), dim3(512), 0, stream>>>
        (nodes, emb_w1t, emb_b1, ln1_g, ln1_b, nullptr, t256_bf, nullptr, nullptr, PP2);
    bgemm_ln_k<2,2,false,true,2,false>
        <<<dim3(BNROWS/128), dim3(256), 0, stream>>>
        (t256_bf, emb_w2t, emb_b2, ln2_g, ln2_b, maskp, nullptr, x_hi, x_lo, 2*DD);

    // ---- ViG blocks ----
    for (int l = 0; l < LLAY; ++l) {
        const float* fc1b = fc1_b + (size_t)l*DD;
        const float* cb   = conv_b + (size_t)l*DD;
        const float* b1   = f1_b + (size_t)l*FFND;
        const float* b2   = f2_b + (size_t)l*DD;

        fc1_dist_topk_gather_k<<<dim3(BB), dim3(1024), 0, stream>>>
            (x_hi, x_lo, fc1_wthi + (size_t)l*DD*DD, fc1_wtlo + (size_t)l*DD*DD,
             fc1b, maskp, cat_bf);
        conv_ffn_k<<<dim3(BNROWS/64), dim3(512), 0, stream>>>
            (cat_bf, conv_wt + (size_t)l*DD*2*DD, cb,
             fc2_wt + (size_t)l*DD*DD, fc2_b + (size_t)l*DD,
             ffn1_wt + (size_t)l*FFND*DD, b1,
             ffn2_wt + (size_t)l*DD*FFND, b2, maskp,
             x_hi, x_lo, gpart);
    }

    // ---- Pool (from layer-2 partials) + head (bf16 MFMA) ----
    pool_k<<<BB, 128, 0, stream>>>(gpart, maskp, g, g_bf);
    bgemm_k<ACT_LRELU,false,false,false,true,false>
        <<<dim3(BB/128, 512/128), blk, 0, stream>>>
        (g_bf, ow1t, ob1, nullptr, nullptr, nullptr, hid2_bf, nullptr, nullptr, BB, 512, DD);
    bgemm_k<ACT_NONE,false,false,true,false,false>
        <<<dim3(BB/128, 2048/128), blk, 0, stream>>>
        (hid2_bf, ow2t, ob2, nullptr, nullptr, out, nullptr, nullptr, nullptr, BB, 2048, 512);
}